// Round 10
// baseline (221.646 us; speedup 1.0000x reference)
//
#include <hip/hip_runtime.h>
#include <hip/hip_bf16.h>
#include <hip/hip_cooperative_groups.h>

// 16-qubit statevector sim, batch 64 — ONE cooperative kernel, 4 phases split by grid.sync().
// idx bit p ("pos p") of state index; wire w <-> pos 15-w. All CRX fused into ctrl-selected
// 1q gates {M0,M1}; all gates register-bit gates; LDS remaps rotate the 4 reg positions.
// L0 tail (F13..F15 + CRX w12..14 + (F12+CRX11) col-0) folded into T2[pos3][pos4][pos0..2].
// Full state packed bf16 (re|im in uint), transposed: saddr=[pos4..15 -> b0..11][pos0..3 -> b12..15].
// Grid: 256 blocks x 512 thr (1 block/CU guaranteed -> cooperative always launches; no VGPR cap).
//   ph0: blocks<64: prep (M0/M1, T2, crx15, zero feats) + L0 12-bit pre (w0..w11) -> pre2 (2 MB).
//   ph1: 2 units/block: T2-expand (factor folded into Gx matrix) + L1 w0..w11, store st (16 MB).
//   ph2: 2 units/block: L1 w12..15 + CRX15, |amp|^2 + PauliZ sums -> feats (atomicAdd).
//   ph3: blocks<64: FC + log_softmax.

namespace cg = cooperative_groups;

#define DIM 65536
#define BATCH 64
#define PSTR 580

template<int RB>
__device__ __forceinline__ void g1q_reg(float* sr, float* si, const float* U) {
  float u00r=U[0],u00i=U[1],u01r=U[2],u01i=U[3],u10r=U[4],u10i=U[5],u11r=U[6],u11i=U[7];
#pragma unroll
  for (int k = 0; k < 8; ++k) {
    int lo = k & ((1<<RB)-1);
    int j0 = ((k >> RB) << (RB+1)) | lo;
    int j1 = j0 | (1<<RB);
    float a0r=sr[j0], a0i=si[j0], a1r=sr[j1], a1i=si[j1];
    sr[j0] = u00r*a0r - u00i*a0i + u01r*a1r - u01i*a1i;
    si[j0] = u00r*a0i + u00i*a0r + u01r*a1i + u01i*a1r;
    sr[j1] = u10r*a0r - u10i*a0i + u11r*a1r - u11i*a1i;
    si[j1] = u10r*a0i + u10i*a0r + u11r*a1i + u11i*a1r;
  }
}

template<int RB, int CB>
__device__ __forceinline__ void gsel_reg_cc(float* sr, float* si, const float* M0, const float* M1) {
  float a0=M0[0],a1=M0[1],a2=M0[2],a3=M0[3],a4=M0[4],a5=M0[5],a6=M0[6],a7=M0[7];
  float b0=M1[0],b1=M1[1],b2=M1[2],b3=M1[3],b4=M1[4],b5=M1[5],b6=M1[6],b7=M1[7];
#pragma unroll
  for (int k = 0; k < 8; ++k) {
    int lo = k & ((1<<RB)-1);
    int j0 = ((k >> RB) << (RB+1)) | lo;
    int j1 = j0 | (1<<RB);
    const bool c = ((j0 >> CB) & 1) != 0;
    float u00r=c?b0:a0, u00i=c?b1:a1, u01r=c?b2:a2, u01i=c?b3:a3;
    float u10r=c?b4:a4, u10i=c?b5:a5, u11r=c?b6:a6, u11i=c?b7:a7;
    float p0r=sr[j0], p0i=si[j0], p1r=sr[j1], p1i=si[j1];
    sr[j0] = u00r*p0r - u00i*p0i + u01r*p1r - u01i*p1i;
    si[j0] = u00r*p0i + u00i*p0r + u01r*p1i + u01i*p1r;
    sr[j1] = u10r*p0r - u10i*p0i + u11r*p1r - u11i*p1i;
    si[j1] = u10r*p0i + u10i*p0r + u11r*p1i + u11i*p1r;
  }
}

template<int RB>
__device__ __forceinline__ void gsel_reg_pred(float* sr, float* si, const float* M0,
                                              const float* M1, bool ctrl) {
  float u[8];
#pragma unroll
  for (int e = 0; e < 8; ++e) u[e] = ctrl ? M1[e] : M0[e];
  g1q_reg<RB>(sr, si, u);
}

template<int CB, int LB>
__device__ __forceinline__ void crx_reg_lane(float* sr, float* si, float c, float s) {
#pragma unroll
  for (int k = 0; k < 8; ++k) {
    int lo2 = k & ((1<<CB)-1);
    int j = ((((k >> CB) << (CB+1)) | lo2)) | (1<<CB);
    float pr = __shfl_xor(sr[j], 1<<LB, 64);
    float pi = __shfl_xor(si[j], 1<<LB, 64);
    float mr = sr[j], mi = si[j];
    sr[j] = c*mr + s*pi;
    si[j] = c*mi - s*pr;
  }
}

__device__ __forceinline__ int swz(int o) { return o ^ ((o>>4)&15) ^ ((o>>8)&15); }

__device__ __forceinline__ unsigned bfp(float r, float i) {
  unsigned ur = __float_as_uint(r), ui = __float_as_uint(i);
  ur = (ur + 0x7fffu + ((ur >> 16) & 1u)) >> 16;
  ui = (ui + 0x7fffu + ((ui >> 16) & 1u)) & 0xffff0000u;
  return (ur & 0xffffu) | ui;
}
__device__ __forceinline__ float bfr(unsigned u) { return __uint_as_float(u << 16); }
__device__ __forceinline__ float bfi(unsigned u) { return __uint_as_float(u & 0xffff0000u); }

#define MP(Pb, l, q, s) ((Pb) + (((l)*16+(q))*2+(s))*8)

__global__ __launch_bounds__(512) void uber(
    const float* __restrict__ x, const float* __restrict__ w0, const float* __restrict__ x0,
    const float* __restrict__ w1, const float* __restrict__ x1, const float* __restrict__ fcw,
    const float* __restrict__ fcb, float* __restrict__ out, unsigned* __restrict__ st,
    float2* __restrict__ pre2, float* __restrict__ P, float* __restrict__ feats) {
  cg::grid_group grid = cg::this_grid();
  __shared__ float2 lds2[8192];
  __shared__ float red[8][17];
  __shared__ float fs[16];
  __shared__ float lg[23];
  int blk = blockIdx.x;
  int t = threadIdx.x, lane = t & 63, wv = t >> 6;

  // ================= phase 0: prep + L0 12-bit pre (blocks < 64) =================
  if (blk < 64) {
    int b = blk;
    float* Pb = P + (size_t)b * PSTR;
    {
      float (*su)[8] = reinterpret_cast<float(*)[8]>(lds2);
      if (t < 16) feats[b*16 + t] = 0.f;
      if (t < 32) {
        int l = t >> 4, q = t & 15;
        const float* W = (l ? w1 : w0) + q*3;
        float xa = 0.5f * x[b*16 + q];
        float cr = cosf(xa), sx = sinf(xa);
        float phi = W[0], th = W[1], om = W[2];
        float ct = cosf(0.5f*th), stt = sinf(0.5f*th);
        float po = 0.5f*(phi+om), pm = 0.5f*(phi-om);
        float ar =  cosf(po)*ct,  ai = -sinf(po)*ct;
        float br = -cosf(pm)*stt, bi = -sinf(pm)*stt;
        float cr2 = cosf(pm)*stt, ci2 = -sinf(pm)*stt;
        float dr =  cosf(po)*ct,  di =  sinf(po)*ct;
        float U[8];
        U[0] = ar*cr + bi*sx;   U[1] = ai*cr - br*sx;
        U[2] = ai*sx + br*cr;   U[3] = -ar*sx + bi*cr;
        U[4] = cr2*cr + di*sx;  U[5] = ci2*cr - dr*sx;
        U[6] = ci2*sx + dr*cr;  U[7] = -cr2*sx + di*cr;
        float* M0 = MP(Pb, l, q, 0);
        float* M1 = M0 + 8;
#pragma unroll
        for (int e = 0; e < 8; ++e) { M0[e] = U[e]; su[t][e] = U[e]; }
        if (q == 0) {
          float ang = l ? 0.5f*x0[15] : 0.f;           // boundary: M1 = U * RX
          float cg2 = cosf(ang), sg = sinf(ang);
          M1[0] =  cg2*U[0] + sg*U[3];  M1[1] = cg2*U[1] - sg*U[2];
          M1[2] =  sg*U[1] + cg2*U[2];  M1[3] = -sg*U[0] + cg2*U[3];
          M1[4] =  cg2*U[4] + sg*U[7];  M1[5] = cg2*U[5] - sg*U[6];
          M1[6] =  sg*U[5] + cg2*U[6];  M1[7] = -sg*U[4] + cg2*U[7];
        } else {
          float ang = 0.5f*(l ? x1[q-1] : x0[q-1]);    // within layer: M1 = RX * U
          float cg2 = cosf(ang), sg = sinf(ang);
          M1[0] = cg2*U[0] + sg*U[5];  M1[1] = cg2*U[1] - sg*U[4];
          M1[2] = cg2*U[2] + sg*U[7];  M1[3] = cg2*U[3] - sg*U[6];
          M1[4] = cg2*U[4] + sg*U[1];  M1[5] = cg2*U[5] - sg*U[0];
          M1[6] = cg2*U[6] + sg*U[3];  M1[7] = cg2*U[7] - sg*U[2];
        }
        if (t == 0) { Pb[576] = cosf(0.5f*x1[15]); Pb[577] = sinf(0.5f*x1[15]); }
      }
      __syncthreads();
      if (t == 0) {
        float T0r[8], T0i[8], T1r[8], T1i[8];
#pragma unroll
        for (int k = 0; k < 8; ++k) {
          int b2 = (k>>2)&1, b1 = (k>>1)&1, b0k = k&1;
          float xr = su[13][b2*4], xi = su[13][b2*4+1];
          float yr = su[14][b1*4], yi = su[14][b1*4+1];
          float zr = su[15][b0k*4], zi = su[15][b0k*4+1];
          float pr = xr*yr - xi*yi, pi = xr*yi + xi*yr;
          T0r[k] = pr*zr - pi*zi; T0i[k] = pr*zi + pi*zr;
        }
        float a12 = 0.5f*x0[12], c12 = cosf(a12), s12 = sinf(a12);
#pragma unroll
        for (int k = 0; k < 8; ++k) { T1r[k] = c12*T0r[k] + s12*T0i[k^4]; T1i[k] = c12*T0i[k] - s12*T0r[k^4]; }
        float a13 = 0.5f*x0[13], c13 = cosf(a13), s13 = sinf(a13);
        float n0r[8], n0i[8], n1r[8], n1i[8];
#pragma unroll
        for (int k = 0; k < 8; ++k) {
          if (k & 4) {
            n0r[k] = c13*T0r[k] + s13*T0i[k^2]; n0i[k] = c13*T0i[k] - s13*T0r[k^2];
            n1r[k] = c13*T1r[k] + s13*T1i[k^2]; n1i[k] = c13*T1i[k] - s13*T1r[k^2];
          } else { n0r[k]=T0r[k]; n0i[k]=T0i[k]; n1r[k]=T1r[k]; n1i[k]=T1i[k]; }
        }
        float a14 = 0.5f*x0[14], c14 = cosf(a14), s14 = sinf(a14);
        float Fr[2][8], Fi[2][8];
#pragma unroll
        for (int k = 0; k < 8; ++k) {
          float r0, i0, r1, i1;
          if (k & 2) {
            r0 = c14*n0r[k] + s14*n0i[k^1]; i0 = c14*n0i[k] - s14*n0r[k^1];
            r1 = c14*n1r[k] + s14*n1i[k^1]; i1 = c14*n1i[k] - s14*n1r[k^1];
          } else { r0=n0r[k]; i0=n0i[k]; r1=n1r[k]; i1=n1i[k]; }
          Fr[0][k] = r0; Fi[0][k] = i0; Fr[1][k] = r1; Fi[1][k] = i1;
        }
        const float* A = MP(Pb,0,12,0);
        const float* B = MP(Pb,0,12,1);
        float wr[2][2], wi[2][2];
        wr[0][0] = A[0]; wi[0][0] = A[1];  wr[1][0] = A[4]; wi[1][0] = A[5];
        wr[0][1] = B[0]; wi[0][1] = B[1];  wr[1][1] = B[4]; wi[1][1] = B[5];
        float* T2 = Pb + 512;
#pragma unroll
        for (int j0 = 0; j0 < 2; ++j0)
#pragma unroll
          for (int j1 = 0; j1 < 2; ++j1)
#pragma unroll
            for (int k = 0; k < 8; ++k) {
              float tr = Fr[j0][k], ti = Fi[j0][k];
              float fr = wr[j0][j1], fi = wi[j0][j1];
              T2[((j0*2 + j1)*8 + k)*2 + 0] = tr*fr - ti*fi;
              T2[((j0*2 + j1)*8 + k)*2 + 1] = tr*fi + ti*fr;
            }
      }
      __syncthreads();
    }
    // L0 12-bit pre (256 active threads; barriers block-wide)
    float sr[16], si[16];
    if (t < 256) {
#pragma unroll
      for (int r = 0; r < 16; ++r) { sr[r] = 0.f; si[r] = 0.f; }
      if (t == 0) sr[0] = 1.f;
      g1q_reg<3>(sr, si, MP(Pb,0,0,0));
      gsel_reg_cc<2,3>(sr, si, MP(Pb,0,1,0), MP(Pb,0,1,1));
      gsel_reg_cc<1,2>(sr, si, MP(Pb,0,2,0), MP(Pb,0,2,1));
      gsel_reg_cc<0,1>(sr, si, MP(Pb,0,3,0), MP(Pb,0,3,1));
#pragma unroll
      for (int r = 0; r < 16; ++r) {
        int o = wv | (lane << 2) | (r << 8);
        lds2[swz(o) & 4095] = make_float2(sr[r], si[r]);
      }
    }
    __syncthreads();
    if (t < 256) {
#pragma unroll
      for (int r = 0; r < 16; ++r) {
        int o = wv | (((lane>>4)&3) << 2) | (r << 4) | ((lane&15) << 8);
        float2 v = lds2[swz(o) & 4095]; sr[r] = v.x; si[r] = v.y;
      }
      gsel_reg_pred<3>(sr, si, MP(Pb,0,4,0), MP(Pb,0,4,1), (lane&1)!=0);
      gsel_reg_cc<2,3>(sr, si, MP(Pb,0,5,0), MP(Pb,0,5,1));
      gsel_reg_cc<1,2>(sr, si, MP(Pb,0,6,0), MP(Pb,0,6,1));
      gsel_reg_cc<0,1>(sr, si, MP(Pb,0,7,0), MP(Pb,0,7,1));
    }
    __syncthreads();
    if (t < 256) {
#pragma unroll
      for (int r = 0; r < 16; ++r) {
        int o = wv | (((lane>>4)&3) << 2) | (r << 4) | ((lane&15) << 8);
        lds2[swz(o) & 4095] = make_float2(sr[r], si[r]);
      }
    }
    __syncthreads();
    if (t < 256) {
#pragma unroll
      for (int r = 0; r < 16; ++r) {
        int o = r | (lane << 4) | (wv << 10);
        float2 v = lds2[swz(o) & 4095]; sr[r] = v.x; si[r] = v.y;
      }
      gsel_reg_pred<3>(sr, si, MP(Pb,0,8,0), MP(Pb,0,8,1), (lane&1)!=0);
      gsel_reg_cc<2,3>(sr, si, MP(Pb,0,9,0), MP(Pb,0,9,1));
      gsel_reg_cc<1,2>(sr, si, MP(Pb,0,10,0), MP(Pb,0,10,1));
      gsel_reg_cc<0,1>(sr, si, MP(Pb,0,11,0), MP(Pb,0,11,1));
#pragma unroll
      for (int r = 0; r < 16; ++r) {
        int paddr = ((lane>>4)&3) | (wv << 2) | (r << 4) | ((lane&15) << 8);
        pre2[(size_t)b*4096 + paddr] = make_float2(sr[r], si[r]);
      }
    }
  }
  grid.sync();

  // ================= phase 1: T2-expand + L1 w0..w11, store st (2 units) =================
#pragma unroll 1
  for (int u = 0; u < 2; ++u) {
    int wu = blk + u*256;
    int b = wu >> 3, m = wu & 7;
    const float* Pb = P + (size_t)b*PSTR;
    float sr[16], si[16];
    __syncthreads();   // lds2 free from previous use
    {
      const float4* src = (const float4*)(pre2 + (size_t)b*4096) + ((lane << 3) | ((wv&3) << 9));
      int k = ((wv>>2)&1) | ((m&3) << 1);
      const float* tf = Pb + 512 + ((((m>>2)&1)*2 + (lane&1))*8 + k)*2;
      float fr = tf[0], fi = tf[1];
#pragma unroll
      for (int g = 0; g < 8; ++g) {
        float4 v = src[g];
        sr[2*g] = v.x; si[2*g] = v.y; sr[2*g+1] = v.z; si[2*g+1] = v.w;
      }
      // Gx (L1 w0, tgt pos15=reg3, ctrl pos0=wv2) with T2 factor folded into the matrix
      const float* M = ((wv>>2)&1) ? MP(Pb,1,0,1) : MP(Pb,1,0,0);
      float v8[8];
#pragma unroll
      for (int e = 0; e < 4; ++e) {
        v8[2*e]   = fr*M[2*e] - fi*M[2*e+1];
        v8[2*e+1] = fr*M[2*e+1] + fi*M[2*e];
      }
      g1q_reg<3>(sr, si, v8);
    }
    gsel_reg_cc<2,3>(sr, si, MP(Pb,1,1,0), MP(Pb,1,1,1));
    gsel_reg_cc<1,2>(sr, si, MP(Pb,1,2,0), MP(Pb,1,2,1));
    gsel_reg_cc<0,1>(sr, si, MP(Pb,1,3,0), MP(Pb,1,3,1));
#pragma unroll
    for (int r = 0; r < 16; ++r) {
      int o = (lane&63) | ((wv&3) << 6) | (r << 8) | (((wv>>2)&1) << 12);
      lds2[swz(o) & 8191] = make_float2(sr[r], si[r]);
    }
    __syncthreads();
#pragma unroll
    for (int r = 0; r < 16; ++r) {
      int o = (lane&15) | (r << 4) | (((lane>>4)&3) << 8) | ((wv&3) << 10) | (((wv>>2)&1) << 12);
      float2 v = lds2[swz(o) & 8191]; sr[r] = v.x; si[r] = v.y;
    }
    gsel_reg_pred<3>(sr, si, MP(Pb,1,4,0), MP(Pb,1,4,1), (lane&16)!=0);
    gsel_reg_cc<2,3>(sr, si, MP(Pb,1,5,0), MP(Pb,1,5,1));
    gsel_reg_cc<1,2>(sr, si, MP(Pb,1,6,0), MP(Pb,1,6,1));
    gsel_reg_cc<0,1>(sr, si, MP(Pb,1,7,0), MP(Pb,1,7,1));
    __syncthreads();
#pragma unroll
    for (int r = 0; r < 16; ++r) {
      int o = (lane&15) | (r << 4) | (((lane>>4)&3) << 8) | ((wv&3) << 10) | (((wv>>2)&1) << 12);
      lds2[swz(o) & 8191] = make_float2(sr[r], si[r]);
    }
    __syncthreads();
#pragma unroll
    for (int r = 0; r < 16; ++r) {
      int o = r | ((lane&63) << 4) | ((wv&3) << 10) | (((wv>>2)&1) << 12);
      float2 v = lds2[swz(o) & 8191]; sr[r] = v.x; si[r] = v.y;
    }
    gsel_reg_pred<3>(sr, si, MP(Pb,1,8,0), MP(Pb,1,8,1), (lane&1)!=0);
    gsel_reg_cc<2,3>(sr, si, MP(Pb,1,9,0), MP(Pb,1,9,1));
    gsel_reg_cc<1,2>(sr, si, MP(Pb,1,10,0), MP(Pb,1,10,1));
    gsel_reg_cc<0,1>(sr, si, MP(Pb,1,11,0), MP(Pb,1,11,1));
    {
      int sbase = ((lane&63) << 4) | ((wv&3) << 10) | (((wv>>2)&1) << 12) | (m << 13);
      uint4* dst = (uint4*)(st + (size_t)b*DIM + sbase);
#pragma unroll
      for (int g = 0; g < 4; ++g)
        dst[g] = make_uint4(bfp(sr[4*g],si[4*g]), bfp(sr[4*g+1],si[4*g+1]),
                            bfp(sr[4*g+2],si[4*g+2]), bfp(sr[4*g+3],si[4*g+3]));
    }
  }
  grid.sync();

  // ================= phase 2: L1 w12..15 + CRX15 + observables (2 units) =================
#pragma unroll 1
  for (int u = 0; u < 2; ++u) {
    int wu = blk + u*256;
    int b = wu >> 3, n = wu & 7;
    const float* Pb = P + (size_t)b*PSTR;
    int base = (lane&31) | (wv << 5) | (n << 8) | ((lane>>5) << 11);
    const unsigned* S = st + (size_t)b*DIM + base;
    float sr[16], si[16];
#pragma unroll
    for (int r = 0; r < 16; ++r) { unsigned uu = S[r << 12]; sr[r] = bfr(uu); si[r] = bfi(uu); }
    gsel_reg_pred<3>(sr, si, MP(Pb,1,12,0), MP(Pb,1,12,1), (lane&1)!=0);
    gsel_reg_cc<2,3>(sr, si, MP(Pb,1,13,0), MP(Pb,1,13,1));
    gsel_reg_cc<1,2>(sr, si, MP(Pb,1,14,0), MP(Pb,1,14,1));
    gsel_reg_cc<0,1>(sr, si, MP(Pb,1,15,0), MP(Pb,1,15,1));
    crx_reg_lane<0,5>(sr, si, Pb[576], Pb[577]);

    float tot=0.f, sA=0.f, sB=0.f, sC=0.f, sD=0.f;
#pragma unroll
    for (int r = 0; r < 16; ++r) {
      float p = sr[r]*sr[r] + si[r]*si[r];
      tot += p;
      sA += (r & 1) ? -p : p;
      sB += (r & 2) ? -p : p;
      sC += (r & 4) ? -p : p;
      sD += (r & 8) ? -p : p;
    }
    float f[16];
    f[15] = sA; f[14] = sB; f[13] = sC; f[12] = sD;
    f[11] = (lane&1)  ? -tot : tot;
    f[10] = (lane&2)  ? -tot : tot;
    f[9]  = (lane&4)  ? -tot : tot;
    f[8]  = (lane&8)  ? -tot : tot;
    f[7]  = (lane&16) ? -tot : tot;
    f[0]  = (lane&32) ? -tot : tot;
    f[6]  = (wv&1)    ? -tot : tot;
    f[5]  = (wv&2)    ? -tot : tot;
    f[4]  = (wv&4)    ? -tot : tot;
    f[3]  = (n&1)     ? -tot : tot;
    f[2]  = (n&2)     ? -tot : tot;
    f[1]  = (n&4)     ? -tot : tot;
#pragma unroll
    for (int w = 0; w < 16; ++w) {
#pragma unroll
      for (int off = 32; off; off >>= 1) f[w] += __shfl_xor(f[w], off, 64);
    }
    __syncthreads();   // red free (prev unit / phase)
    if (lane == 0) {
#pragma unroll
      for (int w = 0; w < 16; ++w) red[wv][w] = f[w];
    }
    __syncthreads();
    if (t < 16) {
      float acc = 0.f;
#pragma unroll
      for (int i = 0; i < 8; ++i) acc += red[i][t];
      atomicAdd(&feats[b*16 + t], acc);
    }
  }
  grid.sync();

  // ================= phase 3: FC + log_softmax (blocks < 64) =================
  if (blk < 64) {
    int b = blk;
    if (t < 16) fs[t] = __hip_atomic_load(&feats[b*16 + t], __ATOMIC_RELAXED, __HIP_MEMORY_SCOPE_AGENT);
    __syncthreads();
    if (t < 23) {
      float acc = fcb[t];
#pragma unroll
      for (int w = 0; w < 16; ++w) acc += fs[w] * fcw[t*16 + w];
      lg[t] = acc;
    }
    __syncthreads();
    if (t < 23) {
      float mx = -1e30f;
#pragma unroll
      for (int j = 0; j < 23; ++j) mx = fmaxf(mx, lg[j]);
      float Ssum = 0.f;
#pragma unroll
      for (int j = 0; j < 23; ++j) Ssum += expf(lg[j] - mx);
      out[b*23 + t] = lg[t] - mx - logf(Ssum);
    }
  }
}

extern "C" void kernel_launch(void* const* d_in, const int* in_sizes, int n_in,
                              void* d_out, int out_size, void* d_ws, size_t ws_size,
                              hipStream_t stream) {
  const float* x   = (const float*)d_in[0];
  const float* w0  = (const float*)d_in[1];
  const float* x0  = (const float*)d_in[2];
  const float* w1  = (const float*)d_in[3];
  const float* x1  = (const float*)d_in[4];
  const float* fcw = (const float*)d_in[5];
  const float* fcb = (const float*)d_in[6];
  float* out = (float*)d_out;

  char* ws = (char*)d_ws;
  unsigned* st  = (unsigned*)ws;                                   // 16 MB
  float2* pre2  = (float2*)(ws + (size_t)BATCH * DIM * 4);         // 2 MB
  float*  P     = (float*)((char*)pre2 + (size_t)BATCH * 4096 * 8);
  float*  feats = P + (size_t)BATCH * PSTR;

  void* args[] = { (void*)&x, (void*)&w0, (void*)&x0, (void*)&w1, (void*)&x1,
                   (void*)&fcw, (void*)&fcb, (void*)&out, (void*)&st, (void*)&pre2,
                   (void*)&P, (void*)&feats };
  hipLaunchCooperativeKernel((const void*)uber, dim3(256), dim3(512), args, 0, stream);
  (void)in_sizes; (void)n_in; (void)out_size; (void)ws_size;
}

// Round 11
// 125.540 us; speedup vs baseline: 1.7655x; 1.7655x over previous
//
#include <hip/hip_runtime.h>
#include <hip/hip_bf16.h>

// 16-qubit statevector sim, batch 64. idx bit p ("pos p") of state index; wire w <-> pos 15-w.
// All CRX fused into ctrl-selected 1q gates {M0,M1}; all gates are register-bit gates; LDS
// remaps rotate which 4 positions live in registers. Intermediate full state is packed bf16
// (re|im in one uint), transposed: saddr = [pos4..15 -> bits0..11][pos0..3 -> bits12..15].
// L0 tail (F13..F15 + CRX w12..14 + (F12+CRX11) col-0) folded into T2[pos3][pos4][pos0..2]:
//   full(pos0..15) = T2[...] * pre(pos4..15),  pre = 12-bit L0 state (w0..w11).
// Pipeline (3 kernels — best measured structure, R9 + Gx-fold micro):
//   pA (64 blk x 256):  prep (M0/M1, T2 table, crx15, zero feats/ctr) + L0 12-bit pre -> pre2.
//   pB (512 blk x 512): T2 factor folded into Gx matrix + L1 w0..w11 (2 remaps), store st (16 MB).
//   p3 (512 blk x 512): L1 w12..15 + CRX15, |amp|^2 + PauliZ sums; 8th arriver does FC.

#define DIM 65536
#define BATCH 64
#define PSTR 580   // per-batch floats in P: 512 matrices + 64 T2 + crx_c + crx_s (+pad)

// ---------------- gate helpers ----------------

template<int RB>
__device__ __forceinline__ void g1q_reg(float* sr, float* si, const float* U) {
  float u00r=U[0],u00i=U[1],u01r=U[2],u01i=U[3],u10r=U[4],u10i=U[5],u11r=U[6],u11i=U[7];
#pragma unroll
  for (int k = 0; k < 8; ++k) {
    int lo = k & ((1<<RB)-1);
    int j0 = ((k >> RB) << (RB+1)) | lo;
    int j1 = j0 | (1<<RB);
    float a0r=sr[j0], a0i=si[j0], a1r=sr[j1], a1i=si[j1];
    sr[j0] = u00r*a0r - u00i*a0i + u01r*a1r - u01i*a1i;
    si[j0] = u00r*a0i + u00i*a0r + u01r*a1i + u01i*a1r;
    sr[j1] = u10r*a0r - u10i*a0i + u11r*a1r - u11i*a1i;
    si[j1] = u10r*a0i + u10i*a0r + u11r*a1i + u11i*a1r;
  }
}

template<int RB, int CB>
__device__ __forceinline__ void gsel_reg_cc(float* sr, float* si, const float* M0, const float* M1) {
  float a0=M0[0],a1=M0[1],a2=M0[2],a3=M0[3],a4=M0[4],a5=M0[5],a6=M0[6],a7=M0[7];
  float b0=M1[0],b1=M1[1],b2=M1[2],b3=M1[3],b4=M1[4],b5=M1[5],b6=M1[6],b7=M1[7];
#pragma unroll
  for (int k = 0; k < 8; ++k) {
    int lo = k & ((1<<RB)-1);
    int j0 = ((k >> RB) << (RB+1)) | lo;
    int j1 = j0 | (1<<RB);
    const bool c = ((j0 >> CB) & 1) != 0;
    float u00r=c?b0:a0, u00i=c?b1:a1, u01r=c?b2:a2, u01i=c?b3:a3;
    float u10r=c?b4:a4, u10i=c?b5:a5, u11r=c?b6:a6, u11i=c?b7:a7;
    float p0r=sr[j0], p0i=si[j0], p1r=sr[j1], p1i=si[j1];
    sr[j0] = u00r*p0r - u00i*p0i + u01r*p1r - u01i*p1i;
    si[j0] = u00r*p0i + u00i*p0r + u01r*p1i + u01i*p1r;
    sr[j1] = u10r*p0r - u10i*p0i + u11r*p1r - u11i*p1i;
    si[j1] = u10r*p0i + u10i*p0r + u11r*p1i + u11i*p1r;
  }
}

template<int RB>
__device__ __forceinline__ void gsel_reg_pred(float* sr, float* si, const float* M0,
                                              const float* M1, bool ctrl) {
  float u[8];
#pragma unroll
  for (int e = 0; e < 8; ++e) u[e] = ctrl ? M1[e] : M0[e];
  g1q_reg<RB>(sr, si, u);
}

template<int CB, int LB>
__device__ __forceinline__ void crx_reg_lane(float* sr, float* si, float c, float s) {
#pragma unroll
  for (int k = 0; k < 8; ++k) {
    int lo2 = k & ((1<<CB)-1);
    int j = ((((k >> CB) << (CB+1)) | lo2)) | (1<<CB);
    float pr = __shfl_xor(sr[j], 1<<LB, 64);
    float pi = __shfl_xor(si[j], 1<<LB, 64);
    float mr = sr[j], mi = si[j];
    sr[j] = c*mr + s*pi;
    si[j] = c*mi - s*pr;
  }
}

__device__ __forceinline__ int swz(int o) { return o ^ ((o>>4)&15) ^ ((o>>8)&15); }

// packed bf16 complex: re in low 16, im in high 16 (RNE rounding)
__device__ __forceinline__ unsigned bfp(float r, float i) {
  unsigned ur = __float_as_uint(r), ui = __float_as_uint(i);
  ur = (ur + 0x7fffu + ((ur >> 16) & 1u)) >> 16;
  ui = (ui + 0x7fffu + ((ui >> 16) & 1u)) & 0xffff0000u;
  return (ur & 0xffffu) | ui;
}
__device__ __forceinline__ float bfr(unsigned u) { return __uint_as_float(u << 16); }
__device__ __forceinline__ float bfi(unsigned u) { return __uint_as_float(u & 0xffff0000u); }

#define MP(Pb, l, q, s) ((Pb) + (((l)*16+(q))*2+(s))*8)

// ---------------- pA: prep + L0 12-bit pre-state (w0..w11), one block per batch ----------------
// i_k = pos_{k+4}. S1: reg=i8..11, l0..5=i2..7, wv=i0,i1.
// S2: reg=i4..7, l0..3=i8..11, l4,5=i2,i3, wv=i0,i1.  S3: reg=i0..3, l0..5=i4..9, wv=i10,i11.
// pre2 paddr = [pos12..15 -> bits0..3][pos4..11 -> bits4..11].

__global__ __launch_bounds__(256) void pA(float2* __restrict__ pre2, float* __restrict__ P,
                                          const float* __restrict__ x, const float* __restrict__ w0,
                                          const float* __restrict__ x0, const float* __restrict__ w1,
                                          const float* __restrict__ x1, float* __restrict__ feats,
                                          int* __restrict__ ctr) {
  __shared__ float2 lds2[4096];   // 32 KB
  int b = blockIdx.x;
  int t = threadIdx.x, lane = t & 63, wv = t >> 6;
  float* Pb = P + (size_t)b * PSTR;

  // ---- prep ----
  {
    float (*su)[8] = reinterpret_cast<float(*)[8]>(lds2);
    if (t < 16) feats[b*16 + t] = 0.f;
    if (t == 16) ctr[b] = 0;
    if (t < 32) {
      int l = t >> 4, q = t & 15;
      const float* W = (l ? w1 : w0) + q*3;
      float xa = 0.5f * x[b*16 + q];
      float cr = cosf(xa), sx = sinf(xa);
      float phi = W[0], th = W[1], om = W[2];
      float ct = cosf(0.5f*th), stt = sinf(0.5f*th);
      float po = 0.5f*(phi+om), pm = 0.5f*(phi-om);
      float ar =  cosf(po)*ct,  ai = -sinf(po)*ct;
      float br = -cosf(pm)*stt, bi = -sinf(pm)*stt;
      float cr2 = cosf(pm)*stt, ci2 = -sinf(pm)*stt;
      float dr =  cosf(po)*ct,  di =  sinf(po)*ct;
      float U[8];
      U[0] = ar*cr + bi*sx;   U[1] = ai*cr - br*sx;
      U[2] = ai*sx + br*cr;   U[3] = -ar*sx + bi*cr;
      U[4] = cr2*cr + di*sx;  U[5] = ci2*cr - dr*sx;
      U[6] = ci2*sx + dr*cr;  U[7] = -cr2*sx + di*cr;
      float* M0 = MP(Pb, l, q, 0);
      float* M1 = M0 + 8;
#pragma unroll
      for (int e = 0; e < 8; ++e) { M0[e] = U[e]; su[t][e] = U[e]; }
      if (q == 0) {
        float ang = l ? 0.5f*x0[15] : 0.f;           // boundary: M1 = U * RX
        float cg = cosf(ang), sg = sinf(ang);
        M1[0] =  cg*U[0] + sg*U[3];  M1[1] = cg*U[1] - sg*U[2];
        M1[2] =  sg*U[1] + cg*U[2];  M1[3] = -sg*U[0] + cg*U[3];
        M1[4] =  cg*U[4] + sg*U[7];  M1[5] = cg*U[5] - sg*U[6];
        M1[6] =  sg*U[5] + cg*U[6];  M1[7] = -sg*U[4] + cg*U[7];
      } else {
        float ang = 0.5f*(l ? x1[q-1] : x0[q-1]);    // within layer: M1 = RX * U
        float cg = cosf(ang), sg = sinf(ang);
        M1[0] = cg*U[0] + sg*U[5];  M1[1] = cg*U[1] - sg*U[4];
        M1[2] = cg*U[2] + sg*U[7];  M1[3] = cg*U[3] - sg*U[6];
        M1[4] = cg*U[4] + sg*U[1];  M1[5] = cg*U[5] - sg*U[0];
        M1[6] = cg*U[6] + sg*U[3];  M1[7] = cg*U[7] - sg*U[2];
      }
      if (t == 0) { Pb[576] = cosf(0.5f*x1[15]); Pb[577] = sinf(0.5f*x1[15]); }
    }
    __syncthreads();
    if (t == 0) {
      // oldT: L0 F13,F14,F15 column-0 products, then CRX w12 branch (a12), w13, w14.
      float T0r[8], T0i[8], T1r[8], T1i[8];
#pragma unroll
      for (int k = 0; k < 8; ++k) {
        int b2 = (k>>2)&1, b1 = (k>>1)&1, b0k = k&1;
        float xr = su[13][b2*4], xi = su[13][b2*4+1];
        float yr = su[14][b1*4], yi = su[14][b1*4+1];
        float zr = su[15][b0k*4], zi = su[15][b0k*4+1];
        float pr = xr*yr - xi*yi, pi = xr*yi + xi*yr;
        T0r[k] = pr*zr - pi*zi; T0i[k] = pr*zi + pi*zr;
      }
      float a12 = 0.5f*x0[12], c12 = cosf(a12), s12 = sinf(a12);
#pragma unroll
      for (int k = 0; k < 8; ++k) { T1r[k] = c12*T0r[k] + s12*T0i[k^4]; T1i[k] = c12*T0i[k] - s12*T0r[k^4]; }
      float a13 = 0.5f*x0[13], c13 = cosf(a13), s13 = sinf(a13);
      float n0r[8], n0i[8], n1r[8], n1i[8];
#pragma unroll
      for (int k = 0; k < 8; ++k) {
        if (k & 4) {
          n0r[k] = c13*T0r[k] + s13*T0i[k^2]; n0i[k] = c13*T0i[k] - s13*T0r[k^2];
          n1r[k] = c13*T1r[k] + s13*T1i[k^2]; n1i[k] = c13*T1i[k] - s13*T1r[k^2];
        } else { n0r[k]=T0r[k]; n0i[k]=T0i[k]; n1r[k]=T1r[k]; n1i[k]=T1i[k]; }
      }
      float a14 = 0.5f*x0[14], c14 = cosf(a14), s14 = sinf(a14);
      float Fr[2][8], Fi[2][8];   // [pos3][k]
#pragma unroll
      for (int k = 0; k < 8; ++k) {
        float r0, i0, r1, i1;
        if (k & 2) {
          r0 = c14*n0r[k] + s14*n0i[k^1]; i0 = c14*n0i[k] - s14*n0r[k^1];
          r1 = c14*n1r[k] + s14*n1i[k^1]; i1 = c14*n1i[k] - s14*n1r[k^1];
        } else { r0=n0r[k]; i0=n0i[k]; r1=n1r[k]; i1=n1i[k]; }
        Fr[0][k] = r0; Fi[0][k] = i0; Fr[1][k] = r1; Fi[1][k] = i1;
      }
      // T2[pos3][pos4][k] = oldT[pos3][k] * w12f(pos3,pos4), w12f = col-0 of (F12+CRX11) gate
      const float* A = MP(Pb,0,12,0);
      const float* B = MP(Pb,0,12,1);
      float wr[2][2], wi[2][2];
      wr[0][0] = A[0]; wi[0][0] = A[1];  wr[1][0] = A[4]; wi[1][0] = A[5];
      wr[0][1] = B[0]; wi[0][1] = B[1];  wr[1][1] = B[4]; wi[1][1] = B[5];
      float* T2 = Pb + 512;
#pragma unroll
      for (int j0 = 0; j0 < 2; ++j0)
#pragma unroll
        for (int j1 = 0; j1 < 2; ++j1)
#pragma unroll
          for (int k = 0; k < 8; ++k) {
            float tr = Fr[j0][k], ti = Fi[j0][k];
            float fr = wr[j0][j1], fi = wi[j0][j1];
            T2[((j0*2 + j1)*8 + k)*2 + 0] = tr*fr - ti*fi;
            T2[((j0*2 + j1)*8 + k)*2 + 1] = tr*fi + ti*fr;
          }
    }
  }

  // ---- L0 12-bit pre-state (w0..w11) ----
  float sr[16], si[16];
#pragma unroll
  for (int r = 0; r < 16; ++r) { sr[r] = 0.f; si[r] = 0.f; }
  if (t == 0) sr[0] = 1.f;

  // S1: w0..w3 (tgt i11..i8 = reg3..0)
  g1q_reg<3>(sr, si, MP(Pb,0,0,0));
  gsel_reg_cc<2,3>(sr, si, MP(Pb,0,1,0), MP(Pb,0,1,1));
  gsel_reg_cc<1,2>(sr, si, MP(Pb,0,2,0), MP(Pb,0,2,1));
  gsel_reg_cc<0,1>(sr, si, MP(Pb,0,3,0), MP(Pb,0,3,1));
  __syncthreads();   // su alias dead before lds2 reuse
#pragma unroll
  for (int r = 0; r < 16; ++r) {
    int o = wv | (lane << 2) | (r << 8);
    lds2[swz(o) & 4095] = make_float2(sr[r], si[r]);
  }
  __syncthreads();
#pragma unroll
  for (int r = 0; r < 16; ++r) {
    int o = wv | (((lane>>4)&3) << 2) | (r << 4) | ((lane&15) << 8);
    float2 v = lds2[swz(o) & 4095]; sr[r] = v.x; si[r] = v.y;
  }
  // S2: w4 (tgt i7=reg3, ctrl i8=l0), w5..w7 (reg2..0)
  gsel_reg_pred<3>(sr, si, MP(Pb,0,4,0), MP(Pb,0,4,1), (lane&1)!=0);
  gsel_reg_cc<2,3>(sr, si, MP(Pb,0,5,0), MP(Pb,0,5,1));
  gsel_reg_cc<1,2>(sr, si, MP(Pb,0,6,0), MP(Pb,0,6,1));
  gsel_reg_cc<0,1>(sr, si, MP(Pb,0,7,0), MP(Pb,0,7,1));
  __syncthreads();
#pragma unroll
  for (int r = 0; r < 16; ++r) {
    int o = wv | (((lane>>4)&3) << 2) | (r << 4) | ((lane&15) << 8);
    lds2[swz(o) & 4095] = make_float2(sr[r], si[r]);
  }
  __syncthreads();
#pragma unroll
  for (int r = 0; r < 16; ++r) {
    int o = r | (lane << 4) | (wv << 10);
    float2 v = lds2[swz(o) & 4095]; sr[r] = v.x; si[r] = v.y;
  }
  // S3: w8 (tgt i3=reg3, ctrl i4=l0), w9..w11 (reg2..0)
  gsel_reg_pred<3>(sr, si, MP(Pb,0,8,0), MP(Pb,0,8,1), (lane&1)!=0);
  gsel_reg_cc<2,3>(sr, si, MP(Pb,0,9,0), MP(Pb,0,9,1));
  gsel_reg_cc<1,2>(sr, si, MP(Pb,0,10,0), MP(Pb,0,10,1));
  gsel_reg_cc<0,1>(sr, si, MP(Pb,0,11,0), MP(Pb,0,11,1));
  // store pre: paddr = [i8..11 -> bits0..3][i0..7 -> bits4..11]
#pragma unroll
  for (int r = 0; r < 16; ++r) {
    int paddr = ((lane>>4)&3) | (wv << 2) | (r << 4) | ((lane&15) << 8);
    pre2[(size_t)b*4096 + paddr] = make_float2(sr[r], si[r]);
  }
}

// ---------------- pB: T2-fold Gx + L1 w1..w11, store packed transposed state ----------------
// block m = pos1,2,3. tile o: o0..11 = pos4..15, o12 = pos0 (= wv2 throughout).
// LA: reg=pos12..15, l0..5=pos4..9, wv0,1=pos10,11
// LB: reg=pos8..11, l0..3=pos4..7, l4,5=pos12,13, wv0,1=pos14,15
// LC: reg=pos4..7, l0..5=pos8..13, wv0,1=pos14,15; store saddr = o | (m<<13)

__global__ __launch_bounds__(512) void pB(unsigned* __restrict__ st, const float2* __restrict__ pre2,
                                          const float* __restrict__ P) {
  __shared__ float2 lds2[8192];
  int blk = blockIdx.x;
  int b = blk >> 3, m = blk & 7;
  int t = threadIdx.x, lane = t & 63, wv = t >> 6;
  const float* Pb = P + (size_t)b*PSTR;

  float sr[16], si[16];
  {
    // load pre (LA: pos4..9=lane, pos10,11=wv&3; varying pos12..15=reg) -> 8x float4
    const float4* src = (const float4*)(pre2 + (size_t)b*4096) + ((lane << 3) | ((wv&3) << 9));
#pragma unroll
    for (int g = 0; g < 8; ++g) {
      float4 v = src[g];
      sr[2*g] = v.x; si[2*g] = v.y; sr[2*g+1] = v.z; si[2*g+1] = v.w;
    }
    // T2 factor: pos0=(wv>>2), pos1,2=m&3, pos3=m>>2, pos4=lane&1 — folded into Gx matrix
    int k = ((wv>>2)&1) | ((m&3) << 1);
    const float* tf = Pb + 512 + ((((m>>2)&1)*2 + (lane&1))*8 + k)*2;
    float fr = tf[0], fi = tf[1];
    const float* M = ((wv>>2)&1) ? MP(Pb,1,0,1) : MP(Pb,1,0,0);  // Gx ctrl pos0=wv2
    float v8[8];
#pragma unroll
    for (int e = 0; e < 4; ++e) {
      v8[2*e]   = fr*M[2*e]   - fi*M[2*e+1];
      v8[2*e+1] = fr*M[2*e+1] + fi*M[2*e];
    }
    g1q_reg<3>(sr, si, v8);   // Gx (L1 w0, tgt pos15=reg3) with factor folded
  }
  gsel_reg_cc<2,3>(sr, si, MP(Pb,1,1,0), MP(Pb,1,1,1));
  gsel_reg_cc<1,2>(sr, si, MP(Pb,1,2,0), MP(Pb,1,2,1));
  gsel_reg_cc<0,1>(sr, si, MP(Pb,1,3,0), MP(Pb,1,3,1));
#pragma unroll
  for (int r = 0; r < 16; ++r) {
    int o = (lane&63) | ((wv&3) << 6) | (r << 8) | (((wv>>2)&1) << 12);
    lds2[swz(o) & 8191] = make_float2(sr[r], si[r]);
  }
  __syncthreads();
#pragma unroll
  for (int r = 0; r < 16; ++r) {
    int o = (lane&15) | (r << 4) | (((lane>>4)&3) << 8) | ((wv&3) << 10) | (((wv>>2)&1) << 12);
    float2 v = lds2[swz(o) & 8191]; sr[r] = v.x; si[r] = v.y;
  }
  // LB: w4 (tgt pos11=reg3, ctrl pos12=l4), w5..w7 (tgt pos10..8)
  gsel_reg_pred<3>(sr, si, MP(Pb,1,4,0), MP(Pb,1,4,1), (lane&16)!=0);
  gsel_reg_cc<2,3>(sr, si, MP(Pb,1,5,0), MP(Pb,1,5,1));
  gsel_reg_cc<1,2>(sr, si, MP(Pb,1,6,0), MP(Pb,1,6,1));
  gsel_reg_cc<0,1>(sr, si, MP(Pb,1,7,0), MP(Pb,1,7,1));
  __syncthreads();
#pragma unroll
  for (int r = 0; r < 16; ++r) {
    int o = (lane&15) | (r << 4) | (((lane>>4)&3) << 8) | ((wv&3) << 10) | (((wv>>2)&1) << 12);
    lds2[swz(o) & 8191] = make_float2(sr[r], si[r]);
  }
  __syncthreads();
#pragma unroll
  for (int r = 0; r < 16; ++r) {
    int o = r | ((lane&63) << 4) | ((wv&3) << 10) | (((wv>>2)&1) << 12);
    float2 v = lds2[swz(o) & 8191]; sr[r] = v.x; si[r] = v.y;
  }
  // LC: w8 (tgt pos7=reg3, ctrl pos8=l0), w9..w11 (tgt pos6..4)
  gsel_reg_pred<3>(sr, si, MP(Pb,1,8,0), MP(Pb,1,8,1), (lane&1)!=0);
  gsel_reg_cc<2,3>(sr, si, MP(Pb,1,9,0), MP(Pb,1,9,1));
  gsel_reg_cc<1,2>(sr, si, MP(Pb,1,10,0), MP(Pb,1,10,1));
  gsel_reg_cc<0,1>(sr, si, MP(Pb,1,11,0), MP(Pb,1,11,1));
  // store packed: saddr0..3 = reg (pos4..7) -> 16 contiguous uints = 4x uint4
  {
    int sbase = ((lane&63) << 4) | ((wv&3) << 10) | (((wv>>2)&1) << 12) | (m << 13);
    uint4* dst = (uint4*)(st + (size_t)b*DIM + sbase);
#pragma unroll
    for (int g = 0; g < 4; ++g)
      dst[g] = make_uint4(bfp(sr[4*g],si[4*g]), bfp(sr[4*g+1],si[4*g+1]),
                          bfp(sr[4*g+2],si[4*g+2]), bfp(sr[4*g+3],si[4*g+3]));
  }
}

// ---------------- p3: L1 w12..15 + CRX15, observables, 8th-arriver FC ----------------
// block n = pos12,13,14 (saddr8..10). reg = pos0..3 (saddr12..15), l0..4 = pos4..8 (saddr0..4),
// l5 = pos15 (saddr11), wv = pos9,10,11 (saddr5..7).

__global__ __launch_bounds__(512) void p3(const unsigned* __restrict__ st, const float* __restrict__ P,
                                          float* __restrict__ feats, int* __restrict__ ctr,
                                          const float* __restrict__ fcw, const float* __restrict__ fcb,
                                          float* __restrict__ out) {
  int blk = blockIdx.x;
  int b = blk >> 3, n = blk & 7;
  int t = threadIdx.x, lane = t & 63, wv = t >> 6;
  const float* Pb = P + (size_t)b*PSTR;
  int base = (lane&31) | (wv << 5) | (n << 8) | ((lane>>5) << 11);
  const unsigned* S = st + (size_t)b*DIM + base;
  float sr[16], si[16];
#pragma unroll
  for (int r = 0; r < 16; ++r) { unsigned u = S[r << 12]; sr[r] = bfr(u); si[r] = bfi(u); }

  gsel_reg_pred<3>(sr, si, MP(Pb,1,12,0), MP(Pb,1,12,1), (lane&1)!=0);
  gsel_reg_cc<2,3>(sr, si, MP(Pb,1,13,0), MP(Pb,1,13,1));
  gsel_reg_cc<1,2>(sr, si, MP(Pb,1,14,0), MP(Pb,1,14,1));
  gsel_reg_cc<0,1>(sr, si, MP(Pb,1,15,0), MP(Pb,1,15,1));
  crx_reg_lane<0,5>(sr, si, Pb[576], Pb[577]);

  float tot=0.f, sA=0.f, sB=0.f, sC=0.f, sD=0.f;
#pragma unroll
  for (int r = 0; r < 16; ++r) {
    float p = sr[r]*sr[r] + si[r]*si[r];
    tot += p;
    sA += (r & 1) ? -p : p;   // pos0 -> wire15
    sB += (r & 2) ? -p : p;   // pos1 -> wire14
    sC += (r & 4) ? -p : p;   // pos2 -> wire13
    sD += (r & 8) ? -p : p;   // pos3 -> wire12
  }
  float f[16];
  f[15] = sA; f[14] = sB; f[13] = sC; f[12] = sD;
  f[11] = (lane&1)  ? -tot : tot;   // pos4
  f[10] = (lane&2)  ? -tot : tot;   // pos5
  f[9]  = (lane&4)  ? -tot : tot;   // pos6
  f[8]  = (lane&8)  ? -tot : tot;   // pos7
  f[7]  = (lane&16) ? -tot : tot;   // pos8
  f[0]  = (lane&32) ? -tot : tot;   // pos15
  f[6]  = (wv&1)    ? -tot : tot;   // pos9
  f[5]  = (wv&2)    ? -tot : tot;   // pos10
  f[4]  = (wv&4)    ? -tot : tot;   // pos11
  f[3]  = (n&1)     ? -tot : tot;   // pos12
  f[2]  = (n&2)     ? -tot : tot;   // pos13
  f[1]  = (n&4)     ? -tot : tot;   // pos14
#pragma unroll
  for (int w = 0; w < 16; ++w) {
#pragma unroll
    for (int off = 32; off; off >>= 1) f[w] += __shfl_xor(f[w], off, 64);
  }
  __shared__ float red[8][17];
  if (lane == 0) {
#pragma unroll
    for (int w = 0; w < 16; ++w) red[wv][w] = f[w];
  }
  __syncthreads();
  if (t < 16) {
    float acc = 0.f;
#pragma unroll
    for (int i = 0; i < 8; ++i) acc += red[i][t];
    atomicAdd(&feats[b*16 + t], acc);
  }

  // last block per batch computes FC + log_softmax
  __shared__ int flagS;
  __syncthreads();
  if (t == 0) { __threadfence(); flagS = atomicAdd(&ctr[b], 1); }
  __syncthreads();
  if (flagS == 7) {
    __shared__ float fs[16];
    __shared__ float lg[23];
    if (t < 16) fs[t] = __hip_atomic_load(&feats[b*16 + t], __ATOMIC_RELAXED, __HIP_MEMORY_SCOPE_AGENT);
    __syncthreads();
    if (t < 23) {
      float acc = fcb[t];
#pragma unroll
      for (int w = 0; w < 16; ++w) acc += fs[w] * fcw[t*16 + w];
      lg[t] = acc;
    }
    __syncthreads();
    if (t < 23) {
      float mx = -1e30f;
#pragma unroll
      for (int j = 0; j < 23; ++j) mx = fmaxf(mx, lg[j]);
      float Ssum = 0.f;
#pragma unroll
      for (int j = 0; j < 23; ++j) Ssum += expf(lg[j] - mx);
      out[b*23 + t] = lg[t] - mx - logf(Ssum);
    }
  }
}

extern "C" void kernel_launch(void* const* d_in, const int* in_sizes, int n_in,
                              void* d_out, int out_size, void* d_ws, size_t ws_size,
                              hipStream_t stream) {
  const float* x   = (const float*)d_in[0];
  const float* w0  = (const float*)d_in[1];
  const float* x0  = (const float*)d_in[2];
  const float* w1  = (const float*)d_in[3];
  const float* x1  = (const float*)d_in[4];
  const float* fcw = (const float*)d_in[5];
  const float* fcb = (const float*)d_in[6];
  float* out = (float*)d_out;

  char* ws = (char*)d_ws;
  unsigned* st  = (unsigned*)ws;                                   // 16 MB
  float2* pre2  = (float2*)(ws + (size_t)BATCH * DIM * 4);         // 2 MB
  float*  P     = (float*)((char*)pre2 + (size_t)BATCH * 4096 * 8);
  float*  feats = P + (size_t)BATCH * PSTR;
  int*    ctr   = (int*)(feats + BATCH*16);

  pA<<<BATCH, 256, 0, stream>>>(pre2, P, x, w0, x0, w1, x1, feats, ctr);
  pB<<<512, 512, 0, stream>>>(st, pre2, P);
  p3<<<512, 512, 0, stream>>>(st, P, feats, ctr, fcw, fcb, out);
  (void)in_sizes; (void)n_in; (void)out_size; (void)ws_size;
}